// Round 9
// baseline (753.200 us; speedup 1.0000x reference)
//
#include <hip/hip_runtime.h>
#include <math.h>

namespace {

constexpr int B = 16, C = 128, H = 64, W = 64;
constexpr int T = W + H - 1;   // 127 diagonal steps
constexpr int SL  = 264;       // scan-loop v slot stride (shorts): 256 + 8 pad
constexpr int XSL = 136;       // pre-gemm x slot stride (shorts): 128 + 8 pad

typedef short bf16x8 __attribute__((ext_vector_type(8)));
typedef float f32x4  __attribute__((ext_vector_type(4)));

// 16B coherent (agent-scope) load as two 64-bit atomics.
__device__ __forceinline__ float4 ld_h16(const float* p) {
    unsigned long long a = __hip_atomic_load((const unsigned long long*)p,
                                             __ATOMIC_RELAXED, __HIP_MEMORY_SCOPE_AGENT);
    unsigned long long b = __hip_atomic_load(((const unsigned long long*)p) + 1,
                                             __ATOMIC_RELAXED, __HIP_MEMORY_SCOPE_AGENT);
    float4 r;
    r.x = __uint_as_float((unsigned)(a & 0xffffffffu));
    r.y = __uint_as_float((unsigned)(a >> 32));
    r.z = __uint_as_float((unsigned)(b & 0xffffffffu));
    r.w = __uint_as_float((unsigned)(b >> 32));
    return r;
}

__device__ __forceinline__ void split1(float v, short& hh, short& ll) {
    const unsigned u = __float_as_uint(v);
    hh = (short)(u >> 16);
    const float r = v - __uint_as_float(u & 0xffff0000u);
    ll = (short)(__float_as_uint(r) >> 16);
}

// Split float4 into bf16 hi + lo residual, write 8B each.
__device__ __forceinline__ void stw(short* hi_p, short* lo_p, int base, float4 f) {
    unsigned ua = __float_as_uint(f.x), ub = __float_as_uint(f.y);
    unsigned h0 = (ua >> 16) | (ub & 0xffff0000u);
    float ra = f.x - __uint_as_float(ua & 0xffff0000u);
    float rb = f.y - __uint_as_float(ub & 0xffff0000u);
    unsigned l0 = (__float_as_uint(ra) >> 16) | (__float_as_uint(rb) & 0xffff0000u);
    unsigned uc = __float_as_uint(f.z), ud = __float_as_uint(f.w);
    unsigned h1 = (uc >> 16) | (ud & 0xffff0000u);
    float rc = f.z - __uint_as_float(uc & 0xffff0000u);
    float rd = f.w - __uint_as_float(ud & 0xffff0000u);
    unsigned l1 = (__float_as_uint(rc) >> 16) | (__float_as_uint(rd) & 0xffff0000u);
    *(uint2*)&hi_p[base] = make_uint2(h0, h1);
    *(uint2*)&lo_p[base] = make_uint2(l0, l1);
}

// ---- pre-GEMM: is[pos][og*64 + cl*4 + g] = (b_is+b_ss) + W_is · x[pos] ----
// Grid: 2048 pos-groups (32 consecutive w of one (b,row)) x 8 og. 512 threads.
__global__ __launch_bounds__(512) void pre_gemm(
        const float* __restrict__ x, const float* __restrict__ w_is,
        const float* __restrict__ b_is, const float* __restrict__ b_ss,
        float* __restrict__ is_out) {
    __shared__ short xhi[32 * XSL];
    __shared__ short xlo[32 * XSL];
    __shared__ float ot[32][68];

    const int og   = blockIdx.x & 7;
    const int pgrp = blockIdx.x >> 3;
    const int b    = pgrp >> 7;
    const int row  = (pgrp >> 1) & 63;
    const int w0   = (pgrp & 1) * 32;
    const int tid  = threadIdx.x;
    const int wave = tid >> 6, l = tid & 63;
    const int ct = wave >> 1, colhalf = wave & 1;
    const int rtile = l & 15, khi = l >> 4;
    const int chl = rtile >> 2, gate = rtile & 3;
    const int wrow = gate * 128 + og * 16 + ct * 4 + chl;

    bf16x8 Ah[4], Al[4];
#pragma unroll
    for (int cc = 0; cc < 4; ++cc)
#pragma unroll
        for (int j = 0; j < 8; ++j) {
            short hh, ll;
            split1(w_is[wrow * 128 + cc * 32 + khi * 8 + j], hh, ll);
            Ah[cc][j] = hh; Al[cc][j] = ll;
        }

    // stage x tile [32 w][128 c] hi/lo (coalesced global float4 reads)
#pragma unroll
    for (int it = 0; it < 2; ++it) {
        const int idx = it * 512 + tid;
        const int c = idx >> 3, wq = (idx & 7) * 4;
        const float4 xv = *(const float4*)&x[((size_t)(b * C + c) * H + row) * W + w0 + wq];
        short hh, ll;
        split1(xv.x, hh, ll); xhi[(wq + 0) * XSL + c] = hh; xlo[(wq + 0) * XSL + c] = ll;
        split1(xv.y, hh, ll); xhi[(wq + 1) * XSL + c] = hh; xlo[(wq + 1) * XSL + c] = ll;
        split1(xv.z, hh, ll); xhi[(wq + 2) * XSL + c] = hh; xlo[(wq + 2) * XSL + c] = ll;
        split1(xv.w, hh, ll); xhi[(wq + 3) * XSL + c] = hh; xlo[(wq + 3) * XSL + c] = ll;
    }
    __syncthreads();

    const int slot = (l & 15) + colhalf * 16;
    const int cl   = ct * 4 + khi;
    const int chO  = og * 16 + cl;
    f32x4 acc;
#pragma unroll
    for (int g = 0; g < 4; ++g) acc[g] = b_is[g * 128 + chO] + b_ss[g * 128 + chO];
#pragma unroll
    for (int cc = 0; cc < 4; ++cc) {
        const int base = slot * XSL + cc * 32 + khi * 8;
        const bf16x8 Bh = *(const bf16x8*)&xhi[base];
        const bf16x8 Bl = *(const bf16x8*)&xlo[base];
        acc = __builtin_amdgcn_mfma_f32_16x16x32_bf16(Ah[cc], Bh, acc, 0, 0, 0);
        acc = __builtin_amdgcn_mfma_f32_16x16x32_bf16(Al[cc], Bh, acc, 0, 0, 0);
        acc = __builtin_amdgcn_mfma_f32_16x16x32_bf16(Ah[cc], Bl, acc, 0, 0, 0);
    }
    *(f32x4*)&ot[slot][cl * 4] = acc;
    __syncthreads();

    const int p2 = tid >> 4, j2 = tid & 15;
    const size_t pos = (size_t)pgrp * 32 + p2;
    *(float4*)&is_out[pos * 512 + og * 64 + j2 * 4] = *(const float4*)&ot[p2][j2 * 4];
}

// ---- persistent diagonal LSTM scan (K = 256 = [h_shift | h]) ----
__global__ __launch_bounds__(512, 2) void lstm_mfma(
        const float* __restrict__ is_in, const float* __restrict__ w_ss,
        float* __restrict__ hist, unsigned int* __restrict__ flags) {

    __shared__ short vhi[32 * SL];
    __shared__ short vlo[32 * SL];

    const int tid  = threadIdx.x;
    const int og   = blockIdx.x & 7;
    const int pg   = blockIdx.x >> 3;
    const int pgm1 = (pg + 31) & 31;
    const int wave = tid >> 6;
    const int l    = tid & 63;
    const int ct   = wave >> 1;
    const int colhalf = wave & 1;

    const int rtile = l & 15, khi = l >> 4;
    const int chl = rtile >> 2, gate = rtile & 3;
    const int wrow = gate * 128 + og * 16 + ct * 4 + chl;

    bf16x8 Ah[8], Al[8];
#pragma unroll
    for (int cc = 0; cc < 8; ++cc)
#pragma unroll
        for (int j = 0; j < 8; ++j) {
            const int k = cc * 32 + khi * 8 + j;
            const float val = (k < 128) ? w_ss[(wrow * 128 + k) * 2 + 0]
                                        : w_ss[(wrow * 128 + (k - 128)) * 2 + 1];
            short hh, ll; split1(val, hh, ll);
            Ah[cc][j] = hh; Al[cc][j] = ll;
        }

    const int slot = (l & 15) + colhalf * 16;
    const int bO   = slot >> 1;
    const int rowO = pg + 32 * (slot & 1);
    const int cl   = ct * 4 + khi;
    const int chO  = og * 16 + cl;
    const int lm   = l & 31;
    float creg = 0.f;

#pragma unroll 1
    for (int t = 0; t < T; ++t) {
        const bool any  = ((unsigned)(t - pg) < 64u) | ((unsigned)(t - pg - 32) < 64u);
        const bool actO = (unsigned)(t - rowO) < 64u;

        // ---- prefetch i_s (no flag dependency; overlaps the poll) ----
        f32x4 is4 = {0.f, 0.f, 0.f, 0.f};
        if (actO) {
            const size_t pos = (size_t)(bO * H + rowO) * W + (t - rowO);
            is4 = *(const f32x4*)&is_in[pos * 512 + og * 64 + cl * 4];
        }

        // ---- wait: parallel poll of 16 single-writer flags ----
        if (any && t > 0) {
            if (tid < 16) {
                const int qg = (tid < 8) ? pg : pgm1;
                const unsigned fidx = (unsigned)(qg * 8 + (tid & 7)) * 32u;
                while (__hip_atomic_load(&flags[fidx], __ATOMIC_RELAXED,
                                         __HIP_MEMORY_SCOPE_AGENT) < (unsigned)t) {}
            }
        }
        __syncthreads();   // S1

        // ---- stage v = [h_shift(128) | h_prev(128)] bf16 hi/lo ----
        if (any) {
#pragma unroll
            for (int i = 0; i < 4; ++i) {
                const int s   = wave * 4 + i;
                const int row = pg + 32 * (s & 1);
                const int w   = t - row;
                if ((unsigned)w < 64u) {
                    const int b = s >> 1;
                    if (l < 32) {
                        float4 hv = make_float4(0.f, 0.f, 0.f, 0.f);
                        if (row > 0)
                            hv = ld_h16(&hist[((size_t)(b * H + row - 1) * W + w) * C + lm * 4]);
                        stw(vhi, vlo, s * SL + lm * 4, hv);
                    } else {
                        float4 hp = make_float4(0.f, 0.f, 0.f, 0.f);
                        if (w > 0)
                            hp = ld_h16(&hist[((size_t)(b * H + row) * W + (w - 1)) * C + lm * 4]);
                        stw(vhi, vlo, s * SL + 128 + lm * 4, hp);
                    }
                }
            }
        }
        __syncthreads();   // S2

        // ---- MFMA: 8 chunks x (AhBh + AlBh + AhBl), acc = i_s ----
        if (any) {
            f32x4 acc = is4;
#pragma unroll
            for (int cc = 0; cc < 8; ++cc) {
                const int base = slot * SL + cc * 32 + khi * 8;
                const bf16x8 Bh = *(const bf16x8*)&vhi[base];
                const bf16x8 Bl = *(const bf16x8*)&vlo[base];
                acc = __builtin_amdgcn_mfma_f32_16x16x32_bf16(Ah[cc], Bh, acc, 0, 0, 0);
                acc = __builtin_amdgcn_mfma_f32_16x16x32_bf16(Al[cc], Bh, acc, 0, 0, 0);
                acc = __builtin_amdgcn_mfma_f32_16x16x32_bf16(Ah[cc], Bl, acc, 0, 0, 0);
            }
            if (actO) {
                const int w = t - rowO;
                const size_t posbase = ((size_t)(bO * H + rowO) * W + w) * C;
                const float o_ = 1.f / (1.f + __expf(-acc[0]));
                const float f_ = 1.f / (1.f + __expf(-acc[1]));
                const float i_ = 1.f / (1.f + __expf(-acc[2]));
                const float g_ = tanhf(acc[3]);
                creg = f_ * creg + i_ * g_;
                const float hn = o_ * tanhf(creg);
                __hip_atomic_store(&hist[posbase + chO], hn,
                                   __ATOMIC_RELAXED, __HIP_MEMORY_SCOPE_AGENT);
            }
        }
        __syncthreads();   // S3: h stores drained (vmcnt(0) before barrier)
        if (tid == 0)
            __hip_atomic_store(&flags[(unsigned)(pg * 8 + og) * 32u], (unsigned)(t + 1),
                               __ATOMIC_RELAXED, __HIP_MEMORY_SCOPE_AGENT);
    }
}

// hist [B][H][W][C] -> out [B][C][H][W]
__global__ void unhist(const float* __restrict__ hist, float* __restrict__ out) {
    __shared__ float tile[W][C + 1];
    int b = blockIdx.x >> 6, row = blockIdx.x & 63;
    int tid = threadIdx.x;
#pragma unroll
    for (int i = 0; i < (C * W) / 256; ++i) {
        int idx = i * 256 + tid;
        int w = idx >> 7, c = idx & 127;
        tile[w][c] = hist[((size_t)(b * H + row) * W + w) * C + c];
    }
    __syncthreads();
#pragma unroll
    for (int i = 0; i < (C * W) / 256; ++i) {
        int idx = i * 256 + tid;
        int c = idx >> 6, w = idx & 63;
        out[((size_t)(b * C + c) * H + row) * W + w] = tile[w][c];
    }
}

} // namespace

extern "C" void kernel_launch(void* const* d_in, const int* in_sizes, int n_in,
                              void* d_out, int out_size, void* d_ws, size_t ws_size,
                              hipStream_t stream) {
    const float* x    = (const float*)d_in[0];
    const float* w_is = (const float*)d_in[1];
    const float* b_is = (const float*)d_in[2];
    const float* w_ss = (const float*)d_in[3];
    const float* b_ss = (const float*)d_in[4];
    float* out = (float*)d_out;

    float* wsf  = (float*)d_ws;
    float* is_b = wsf;                                   // B*H*W*512 floats (134 MB)
    float* hist = is_b + (size_t)B * H * W * 512;        // B*H*W*C floats (33.5 MB)
    unsigned int* flags = (unsigned int*)(hist + (size_t)B * H * W * C);  // 256*32 u32

    hipMemsetAsync(flags, 0, 256 * 32 * sizeof(unsigned int), stream);
    hipLaunchKernelGGL(pre_gemm, dim3(2048 * 8), dim3(512), 0, stream,
                       x, w_is, b_is, b_ss, is_b);

    void* args[] = { (void*)&is_b, (void*)&w_ss, (void*)&hist, (void*)&flags };
    hipLaunchCooperativeKernel((const void*)lstm_mfma, dim3(256), dim3(512),
                               args, 0, stream);

    hipLaunchKernelGGL(unhist, dim3(B * H), dim3(256), 0, stream, hist, out);
}